// Round 2
// baseline (778.410 us; speedup 1.0000x reference)
//
#include <hip/hip_runtime.h>

typedef unsigned short u16;
typedef unsigned int u32;
typedef __attribute__((ext_vector_type(8))) __bf16 bf16x8;
typedef __attribute__((ext_vector_type(4))) float f32x4;

#define SEQ   2048
#define NH    71
#define HD    64
#define HID   4544   // 71*64
#define NQKV  4672   // 73*64

__device__ __forceinline__ u16 f2bf(float f) {
    __bf16 b = (__bf16)f;
    return __builtin_bit_cast(u16, b);
}

__device__ __forceinline__ void gload_lds16(const u16* g, u16* l) {
    __builtin_amdgcn_global_load_lds(
        (const __attribute__((address_space(1))) u32*)g,
        (__attribute__((address_space(3))) u32*)l, 16, 0, 0);
}

// ---------------- f32 -> bf16 elementwise (x) ----------------
__global__ __launch_bounds__(256) void k_convert(const float* __restrict__ in,
                                                 u16* __restrict__ out, int n4) {
    for (int i = blockIdx.x * 256 + threadIdx.x; i < n4; i += gridDim.x * 256) {
        float4 v = ((const float4*)in)[i];
        ushort4 o;
        o.x = f2bf(v.x); o.y = f2bf(v.y); o.z = f2bf(v.z); o.w = f2bf(v.w);
        ((ushort4*)out)[i] = o;
    }
}

// ------------- transpose+convert: in[R][C] f32 -> out[C][R] bf16 -------------
__global__ __launch_bounds__(256) void k_transpose(const float* __restrict__ in,
                                                   u16* __restrict__ out, int R, int C) {
    __shared__ float tile[32][33];
    int c0 = blockIdx.x * 32, r0 = blockIdx.y * 32;
    int tx = threadIdx.x & 31, ty = threadIdx.x >> 5;
#pragma unroll
    for (int i = 0; i < 32; i += 8)
        tile[ty + i][tx] = in[(size_t)(r0 + ty + i) * C + c0 + tx];
    __syncthreads();
#pragma unroll
    for (int i = 0; i < 32; i += 8)
        out[(size_t)(c0 + ty + i) * R + r0 + tx] = f2bf(tile[tx][ty + i]);
}

// ---- C[M][N] f32 = A[M][K] bf16 @ BT[N][K]^T (m97 structure, 128x128, BK=32) ----
// XCD-aware block swizzle (requires nwg % 8 == 0 -- true for 592 and 576).
__global__ __launch_bounds__(256) void k_gemm_bt(const u16* __restrict__ A,
                                                 const u16* __restrict__ BT,
                                                 float* __restrict__ C,
                                                 int M, int N, int K) {
    __shared__ u16 lsA[128 * 32];
    __shared__ u16 lsB[128 * 32];
    const int tid = threadIdx.x;
    const int lane = tid & 63;
    const int wid = tid >> 6;
    const int wr = wid >> 1, wc = wid & 1;
    const int l15 = lane & 15, lg = lane >> 4;

    const int nwg = gridDim.x * gridDim.y;
    int lin = blockIdx.y * gridDim.x + blockIdx.x;
    lin = (lin & 7) * (nwg >> 3) + (lin >> 3);
    const int m0 = (lin / gridDim.x) * 128;
    const int n0 = (lin % gridDim.x) * 128;

    f32x4 acc[4][4];
#pragma unroll
    for (int i = 0; i < 4; ++i)
#pragma unroll
        for (int j = 0; j < 4; ++j) acc[i][j] = (f32x4){0.f, 0.f, 0.f, 0.f};

    for (int k0 = 0; k0 < K; k0 += 32) {
#pragma unroll
        for (int i = 0; i < 2; ++i) {
            int ch = i * 256 + tid;
            int row = ch >> 2;
            int c8 = ch & 3;
            gload_lds16(A + (size_t)(m0 + row) * K + k0 + c8 * 8, lsA + ch * 8);
            gload_lds16(BT + (size_t)(n0 + row) * K + k0 + c8 * 8, lsB + ch * 8);
        }
        __syncthreads();
        bf16x8 af[4], bfr[4];
#pragma unroll
        for (int mi = 0; mi < 4; ++mi)
            af[mi] = *(const bf16x8*)(lsA + (wr * 64 + mi * 16 + l15) * 32 + lg * 8);
#pragma unroll
        for (int ni = 0; ni < 4; ++ni)
            bfr[ni] = *(const bf16x8*)(lsB + (wc * 64 + ni * 16 + l15) * 32 + lg * 8);
#pragma unroll
        for (int mi = 0; mi < 4; ++mi)
#pragma unroll
            for (int ni = 0; ni < 4; ++ni)
                acc[mi][ni] = __builtin_amdgcn_mfma_f32_16x16x32_bf16(
                    af[mi], bfr[ni], acc[mi][ni], 0, 0, 0);
        __syncthreads();
    }
#pragma unroll
    for (int mi = 0; mi < 4; ++mi)
#pragma unroll
        for (int ni = 0; ni < 4; ++ni) {
            int row = m0 + wr * 64 + mi * 16 + lg * 4;
            int col = n0 + wc * 64 + ni * 16 + l15;
            if (col < N) {
#pragma unroll
                for (int j = 0; j < 4; ++j)
                    C[(size_t)(row + j) * N + col] = acc[mi][ni][j];
            }
        }
}

// ---------------- RoPE + split/transposed emit ----------------
// q pre-scaled by (1/8)*log2(e) so attention softmax can use exp2 directly.
__global__ __launch_bounds__(256) void k_rope(const float* __restrict__ qkv,
                                              const float* __restrict__ cosb,
                                              const float* __restrict__ sinb,
                                              u16* __restrict__ qb, u16* __restrict__ kb,
                                              u16* __restrict__ vT) {
    int s = blockIdx.x;
    __shared__ float cs[64], sn[64];
    if (threadIdx.x < 64) {
        cs[threadIdx.x] = cosb[s * 64 + threadIdx.x];
        sn[threadIdx.x] = sinb[s * 64 + threadIdx.x];
    }
    __syncthreads();
    const float* row = qkv + (size_t)s * NQKV;
    const float qscale = 0.125f * 1.44269504f;
    for (int e = threadIdx.x; e < NQKV; e += 256) {
        int h = e >> 6, d = e & 63;
        float x = row[e];
        if (h < 72) {
            float other = row[h * 64 + ((d < 32) ? d + 32 : d - 32)];
            float rot = (d < 32) ? -other : other;
            float r = x * cs[d] + rot * sn[d];
            if (h < NH) qb[((size_t)h * SEQ + s) * 64 + d] = f2bf(r * qscale);
            else        kb[(size_t)s * 64 + d] = f2bf(r);
        } else {
            vT[(size_t)d * SEQ + s] = f2bf(x);
        }
    }
}

// ---------------- Flash attention: barrier-free waves, swapped QK^T ----------------
// One wave per (head, 32 q-rows). K/V fragments loaded directly from global (L2-hot).
// S^T = mfma(K, Q): lane (l15,lg) holds S[q=q0+mi*16+l15][t=t0+ni*16+lg*4+jj].
// Softmax row-reduce: lane-local over 32 + 2 shfl_xor across the 4 lg lanes.
// P staged per-wave in swizzled LDS as b64 writes; PV reads b128 A-fragments.
__global__ __launch_bounds__(256) void k_attn(const u16* __restrict__ qb,
                                              const u16* __restrict__ kb,
                                              const u16* __restrict__ vT,
                                              u16* __restrict__ ctx) {
    const int tid = threadIdx.x;
    const int lane = tid & 63;
    const int wid = tid >> 6;
    const int l15 = lane & 15, lg = lane >> 4;

    const int g = blockIdx.x * 4 + wid;        // 0..4543
    const int h = g >> 6;                      // 0..70
    const int chunk = 63 - (g & 63);           // long chunks dispatch first
    const int q0 = chunk * 32;

    __shared__ u16 lsP[4][4096];               // per-wave P: 32 rows x 256B, swizzled
    u16* myP = lsP[wid];

    // Q B-fragments (col = l15 -> q, k = lg*8+j -> d)
    bf16x8 qf[2][2];
#pragma unroll
    for (int mi = 0; mi < 2; ++mi)
#pragma unroll
        for (int ks = 0; ks < 2; ++ks)
            qf[mi][ks] = *(const bf16x8*)(qb + ((size_t)h * SEQ + q0 + mi * 16 + l15) * 64
                                          + ks * 32 + lg * 8);

    f32x4 oacc[2][4];
#pragma unroll
    for (int i = 0; i < 2; ++i)
#pragma unroll
        for (int j = 0; j < 4; ++j) oacc[i][j] = (f32x4){0.f, 0.f, 0.f, 0.f};
    float mrun[2] = {-3e38f, -3e38f};
    float lrun[2] = {0.f, 0.f};

    const int ntiles = (q0 >> 7) + 1;
    for (int t = 0; t < ntiles; ++t) {
        const int t0 = t << 7;
        // ---- S^T = K @ Q : sacc[mi][ni][jj] = S[q0+mi*16+l15][t0+ni*16+lg*4+jj]
        f32x4 sacc[2][8];
#pragma unroll
        for (int i = 0; i < 2; ++i)
#pragma unroll
            for (int j = 0; j < 8; ++j) sacc[i][j] = (f32x4){0.f, 0.f, 0.f, 0.f};
#pragma unroll
        for (int ni = 0; ni < 8; ++ni) {
            const u16* kp = kb + (size_t)(t0 + ni * 16 + l15) * 64 + lg * 8;
            bf16x8 kf0 = *(const bf16x8*)kp;
            bf16x8 kf1 = *(const bf16x8*)(kp + 32);
            sacc[0][ni] = __builtin_amdgcn_mfma_f32_16x16x32_bf16(kf0, qf[0][0], sacc[0][ni], 0, 0, 0);
            sacc[1][ni] = __builtin_amdgcn_mfma_f32_16x16x32_bf16(kf0, qf[1][0], sacc[1][ni], 0, 0, 0);
            sacc[0][ni] = __builtin_amdgcn_mfma_f32_16x16x32_bf16(kf1, qf[0][1], sacc[0][ni], 0, 0, 0);
            sacc[1][ni] = __builtin_amdgcn_mfma_f32_16x16x32_bf16(kf1, qf[1][1], sacc[1][ni], 0, 0, 0);
        }
        const bool last = (t == ntiles - 1);

        // ---- online softmax (per mi: q = q0 + mi*16 + l15, replicated over lg)
#pragma unroll
        for (int mi = 0; mi < 2; ++mi) {
            const int q = q0 + mi * 16 + l15;
            if (last) {
#pragma unroll
                for (int ni = 0; ni < 8; ++ni)
#pragma unroll
                    for (int jj = 0; jj < 4; ++jj)
                        if (t0 + ni * 16 + lg * 4 + jj > q) sacc[mi][ni][jj] = -1e9f;
            }
            float m = sacc[mi][0][0];
#pragma unroll
            for (int ni = 0; ni < 8; ++ni)
#pragma unroll
                for (int jj = 0; jj < 4; ++jj) m = fmaxf(m, sacc[mi][ni][jj]);
            m = fmaxf(m, __shfl_xor(m, 16, 64));
            m = fmaxf(m, __shfl_xor(m, 32, 64));
            float mnew = fmaxf(mrun[mi], m);
            float alpha = exp2f(mrun[mi] - mnew);
            float rs = 0.f;
#pragma unroll
            for (int ni = 0; ni < 8; ++ni)
#pragma unroll
                for (int jj = 0; jj < 4; ++jj) {
                    float p = exp2f(sacc[mi][ni][jj] - mnew);
                    sacc[mi][ni][jj] = p;
                    rs += p;
                }
            rs += __shfl_xor(rs, 16, 64);
            rs += __shfl_xor(rs, 32, 64);
            lrun[mi] = lrun[mi] * alpha + rs;
            mrun[mi] = mnew;

            // P -> LDS: lane holds t = ni*16 + lg*4 + {0..3} for row qh
            const int qh = mi * 16 + l15;
            const int swz = (qh & 7) << 4;
#pragma unroll
            for (int ni = 0; ni < 8; ++ni) {
                u32 w0 = (u32)f2bf(sacc[mi][ni][0]) | ((u32)f2bf(sacc[mi][ni][1]) << 16);
                u32 w1 = (u32)f2bf(sacc[mi][ni][2]) | ((u32)f2bf(sacc[mi][ni][3]) << 16);
                uint2 w; w.x = w0; w.y = w1;
                *(uint2*)((char*)myP + qh * 256 + ((ni * 32 + lg * 8) ^ swz)) = w;
            }
            // rescale O rows (row index = lg*4+jj) by alpha broadcast from lane l15=lg*4+jj
#pragma unroll
            for (int jj = 0; jj < 4; ++jj) {
                float aB = __shfl(alpha, (lane & 48) + ((lane >> 4) & 3) * 4 + jj, 64);
#pragma unroll
                for (int nd = 0; nd < 4; ++nd) oacc[mi][nd][jj] *= aB;
            }
        }

        // ---- O += P @ V  (pf: A-frag from LDS; vf: B-frag direct from global vT)
#pragma unroll
        for (int ks = 0; ks < 4; ++ks) {
            bf16x8 pf[2];
#pragma unroll
            for (int mi = 0; mi < 2; ++mi) {
                const int qh = mi * 16 + l15;
                pf[mi] = *(const bf16x8*)((const char*)myP + qh * 256
                                          + ((ks * 64 + lg * 16) ^ ((qh & 7) << 4)));
            }
#pragma unroll
            for (int nd = 0; nd < 4; ++nd) {
                bf16x8 vf = *(const bf16x8*)(vT + (size_t)(nd * 16 + l15) * SEQ
                                             + t0 + ks * 32 + lg * 8);
                oacc[0][nd] = __builtin_amdgcn_mfma_f32_16x16x32_bf16(pf[0], vf, oacc[0][nd], 0, 0, 0);
                oacc[1][nd] = __builtin_amdgcn_mfma_f32_16x16x32_bf16(pf[1], vf, oacc[1][nd], 0, 0, 0);
            }
        }
    }

    // ---- epilogue: O /= l ; ctx[q][h*64+d]
#pragma unroll
    for (int mi = 0; mi < 2; ++mi)
#pragma unroll
        for (int jj = 0; jj < 4; ++jj) {
            float lB = __shfl(lrun[mi], (lane & 48) + ((lane >> 4) & 3) * 4 + jj, 64);
            float inv = 1.0f / lB;
            int q = q0 + mi * 16 + lg * 4 + jj;
#pragma unroll
            for (int nd = 0; nd < 4; ++nd)
                ctx[(size_t)q * HID + h * 64 + nd * 16 + l15] = f2bf(oacc[mi][nd][jj] * inv);
        }
}

extern "C" void kernel_launch(void* const* d_in, const int* in_sizes, int n_in,
                              void* d_out, int out_size, void* d_ws, size_t ws_size,
                              hipStream_t stream) {
    const float* hs      = (const float*)d_in[0];
    const float* w_qkv   = (const float*)d_in[2];
    const float* w_dense = (const float*)d_in[3];
    const float* cosb    = (const float*)d_in[4];
    const float* sinb    = (const float*)d_in[5];
    float* out = (float*)d_out;

    char* ws = (char*)d_ws;
    u16*   x_bf  = (u16*)(ws + 0);            // [2048][4544] bf16; reused as ctx
    u16*   wqkvT = (u16*)(ws + 18612224);     // [4736][4544] bf16
    u16*   wdenT = (u16*)(ws + 61652992);     // [4608][4544] bf16
    float* qkv   = (float*)(ws + 103530496);  // [2048][4672] f32
    u16*   q_bf  = (u16*)(ws + 141803520);    // [71][2048][64] bf16 (scaled)
    u16*   k_bf  = (u16*)(ws + 160415744);    // [2048][64] bf16
    u16*   vT_bf = (u16*)(ws + 160677888);    // [64][2048] bf16

    k_convert<<<2048, 256, 0, stream>>>(hs, x_bf, (SEQ * HID) / 4);
    k_transpose<<<dim3(NQKV / 32, HID / 32), 256, 0, stream>>>(w_qkv, wqkvT, HID, NQKV);
    k_transpose<<<dim3(HID / 32, HID / 32), 256, 0, stream>>>(w_dense, wdenT, HID, HID);
    k_gemm_bt<<<dim3(37, 16), 256, 0, stream>>>(x_bf, wqkvT, qkv, SEQ, NQKV, HID);
    k_rope<<<SEQ, 256, 0, stream>>>(qkv, cosb, sinb, q_bf, k_bf, vT_bf);
    k_attn<<<dim3(1136), 256, 0, stream>>>(q_bf, k_bf, vT_bf, x_bf /*ctx*/);
    k_gemm_bt<<<dim3(36, 16), 256, 0, stream>>>(x_bf /*ctx*/, wdenT, out, SEQ, HID, HID);
}

// Round 3
// 513.577 us; speedup vs baseline: 1.5157x; 1.5157x over previous
//
#include <hip/hip_runtime.h>

typedef unsigned short u16;
typedef unsigned int u32;
typedef __attribute__((ext_vector_type(8))) __bf16 bf16x8;
typedef __attribute__((ext_vector_type(4))) float f32x4;

#define SEQ   2048
#define NH    71
#define HD    64
#define HID   4544   // 71*64
#define NQKV  4672   // 73*64

__device__ __forceinline__ u16 f2bf(float f) {
    __bf16 b = (__bf16)f;
    return __builtin_bit_cast(u16, b);
}

__device__ __forceinline__ void gload_lds16(const u16* g, u16* l) {
    __builtin_amdgcn_global_load_lds(
        (const __attribute__((address_space(1))) u32*)g,
        (__attribute__((address_space(3))) u32*)l, 16, 0, 0);
}

// ---------------- f32 -> bf16 elementwise (x) ----------------
__global__ __launch_bounds__(256) void k_convert(const float* __restrict__ in,
                                                 u16* __restrict__ out, int n4) {
    for (int i = blockIdx.x * 256 + threadIdx.x; i < n4; i += gridDim.x * 256) {
        float4 v = ((const float4*)in)[i];
        ushort4 o;
        o.x = f2bf(v.x); o.y = f2bf(v.y); o.z = f2bf(v.z); o.w = f2bf(v.w);
        ((ushort4*)out)[i] = o;
    }
}

// ------------- transpose+convert: in[R][C] f32 -> out[C][R] bf16 -------------
__global__ __launch_bounds__(256) void k_transpose(const float* __restrict__ in,
                                                   u16* __restrict__ out, int R, int C) {
    __shared__ float tile[32][33];
    int c0 = blockIdx.x * 32, r0 = blockIdx.y * 32;
    int tx = threadIdx.x & 31, ty = threadIdx.x >> 5;
#pragma unroll
    for (int i = 0; i < 32; i += 8)
        tile[ty + i][tx] = in[(size_t)(r0 + ty + i) * C + c0 + tx];
    __syncthreads();
#pragma unroll
    for (int i = 0; i < 32; i += 8)
        out[(size_t)(c0 + ty + i) * R + r0 + tx] = f2bf(tile[tx][ty + i]);
}

// ---- C[M][N] f32 = A[M][K] bf16 @ BT[N][K]^T (128x128 tile, BK=64) ----
// global_load_lds staging with source-pre-swizzled chunks so the [128][64]
// LDS tiles read conflict-free (chunk j of row r holds global chunk j^(r&7)).
__global__ __launch_bounds__(256) void k_gemm_bt(const u16* __restrict__ A,
                                                 const u16* __restrict__ BT,
                                                 float* __restrict__ C,
                                                 int M, int N, int K) {
    __shared__ u16 lsA[128 * 64];
    __shared__ u16 lsB[128 * 64];
    const int tid = threadIdx.x;
    const int lane = tid & 63;
    const int wid = tid >> 6;
    const int wr = wid >> 1, wc = wid & 1;
    const int l15 = lane & 15, lg = lane >> 4;

    const int nwg = gridDim.x * gridDim.y;
    int lin = blockIdx.y * gridDim.x + blockIdx.x;
    lin = (lin & 7) * (nwg >> 3) + (lin >> 3);
    const int m0 = (lin / gridDim.x) * 128;
    const int n0 = (lin % gridDim.x) * 128;

    f32x4 acc[4][4];
#pragma unroll
    for (int i = 0; i < 4; ++i)
#pragma unroll
        for (int j = 0; j < 4; ++j) acc[i][j] = (f32x4){0.f, 0.f, 0.f, 0.f};

    for (int k0 = 0; k0 < K; k0 += 64) {
#pragma unroll
        for (int i = 0; i < 4; ++i) {
            int ch = i * 256 + tid;            // 0..1023
            int row = ch >> 3;
            int c = ch & 7;
            int cs = c ^ (row & 7);            // source chunk (pre-swizzle)
            gload_lds16(A + (size_t)(m0 + row) * K + k0 + cs * 8, lsA + ch * 8);
            gload_lds16(BT + (size_t)(n0 + row) * K + k0 + cs * 8, lsB + ch * 8);
        }
        __syncthreads();
#pragma unroll
        for (int ks = 0; ks < 2; ++ks) {
            bf16x8 af[4], bfr[4];
#pragma unroll
            for (int mi = 0; mi < 4; ++mi) {
                int r = wr * 64 + mi * 16 + l15;
                af[mi] = *(const bf16x8*)((const char*)lsA + r * 128
                                          + (((ks * 4 + lg) ^ (r & 7)) << 4));
            }
#pragma unroll
            for (int ni = 0; ni < 4; ++ni) {
                int r = wc * 64 + ni * 16 + l15;
                bfr[ni] = *(const bf16x8*)((const char*)lsB + r * 128
                                           + (((ks * 4 + lg) ^ (r & 7)) << 4));
            }
#pragma unroll
            for (int mi = 0; mi < 4; ++mi)
#pragma unroll
                for (int ni = 0; ni < 4; ++ni)
                    acc[mi][ni] = __builtin_amdgcn_mfma_f32_16x16x32_bf16(
                        af[mi], bfr[ni], acc[mi][ni], 0, 0, 0);
        }
        __syncthreads();
    }
#pragma unroll
    for (int mi = 0; mi < 4; ++mi)
#pragma unroll
        for (int ni = 0; ni < 4; ++ni) {
            int row = m0 + wr * 64 + mi * 16 + lg * 4;
            int col = n0 + wc * 64 + ni * 16 + l15;
            if (col < N) {
#pragma unroll
                for (int j = 0; j < 4; ++j)
                    C[(size_t)(row + j) * N + col] = acc[mi][ni][j];
            }
        }
}

// ---------------- RoPE + split/transposed emit ----------------
// q pre-scaled by (1/8)*log2(e) so attention softmax can use exp2 directly.
__global__ __launch_bounds__(256) void k_rope(const float* __restrict__ qkv,
                                              const float* __restrict__ cosb,
                                              const float* __restrict__ sinb,
                                              u16* __restrict__ qb, u16* __restrict__ kb,
                                              u16* __restrict__ vT) {
    int s = blockIdx.x;
    __shared__ float cs[64], sn[64];
    if (threadIdx.x < 64) {
        cs[threadIdx.x] = cosb[s * 64 + threadIdx.x];
        sn[threadIdx.x] = sinb[s * 64 + threadIdx.x];
    }
    __syncthreads();
    const float* row = qkv + (size_t)s * NQKV;
    const float qscale = 0.125f * 1.44269504f;
    for (int e = threadIdx.x; e < NQKV; e += 256) {
        int h = e >> 6, d = e & 63;
        float x = row[e];
        if (h < 72) {
            float other = row[h * 64 + ((d < 32) ? d + 32 : d - 32)];
            float rot = (d < 32) ? -other : other;
            float r = x * cs[d] + rot * sn[d];
            if (h < NH) qb[((size_t)h * SEQ + s) * 64 + d] = f2bf(r * qscale);
            else        kb[(size_t)s * 64 + d] = f2bf(r);
        } else {
            vT[(size_t)d * SEQ + s] = f2bf(x);
        }
    }
}

// ---------------- Flash attention: MQA head-group sharing + dbuf staging ----------------
// Block = 512 threads (8 waves) = (q-tile of 32 rows, group of 8 heads); wave w -> head
// hg*8+w, all waves share the staged K/V tile (8x reuse per stage). KV tiles of 128,
// double-buffered LDS with T14 async split (issue global loads early, ds_write after
// the single per-tile barrier). Swapped QK^T (S^T = K@Q) for lane-local softmax rows.
__global__ __launch_bounds__(512) void k_attn(const u16* __restrict__ qb,
                                              const u16* __restrict__ kb,
                                              const u16* __restrict__ vT,
                                              u16* __restrict__ ctx) {
    const int tid = threadIdx.x;
    const int lane = tid & 63;
    const int wid = tid >> 6;           // 0..7
    const int l15 = lane & 15, lg = lane >> 4;

    const int bid = blockIdx.x;         // 0..575
    const int qt = 63 - bid / 9;        // long blocks dispatch first
    const int hg = bid % 9;
    int h = hg * 8 + wid;
    const bool hval = (h < NH);
    if (!hval) h = NH - 1;
    const int q0 = qt * 32;
    const int nt = (qt >> 2) + 1;

    __shared__ u16 lsK[2][128 * 64];    // [t][d] rows 128B, XOR-swizzled
    __shared__ u16 lsV[2][64 * 128];    // [d][t] rows 256B, XOR-swizzled
    __shared__ u16 lsP[8][32 * 128];    // per-wave P, rows 256B, XOR-swizzled
    u16* myP = lsP[wid];

    // staging chunk ids (512 threads; 1024 16B-chunks per matrix -> 2 each)
    const int kr = tid >> 3, kc = tid & 7;    // rows kr and kr+64
    const int vd = tid >> 4, vc = tid & 15;   // rows vd and vd+32

    // Q B-fragments (col=l15 -> q, k=lg*8+j -> d); q pre-scaled
    bf16x8 qf[2][2];
#pragma unroll
    for (int mi = 0; mi < 2; ++mi)
#pragma unroll
        for (int ks = 0; ks < 2; ++ks)
            qf[mi][ks] = *(const bf16x8*)(qb + ((size_t)h * SEQ + q0 + mi * 16 + l15) * 64
                                          + ks * 32 + lg * 8);

    f32x4 oacc[2][4];
#pragma unroll
    for (int i = 0; i < 2; ++i)
#pragma unroll
        for (int j = 0; j < 4; ++j) oacc[i][j] = (f32x4){0.f, 0.f, 0.f, 0.f};
    float mrun[2] = {-3e38f, -3e38f};
    float lrun[2] = {0.f, 0.f};

    // ---- prologue: load tile 0 and write to buffer 0
    uint4 kg0, kg1, vg0, vg1;
    kg0 = *(const uint4*)(kb + (size_t)kr * 64 + kc * 8);
    kg1 = *(const uint4*)(kb + (size_t)(kr + 64) * 64 + kc * 8);
    vg0 = *(const uint4*)(vT + (size_t)vd * SEQ + vc * 8);
    vg1 = *(const uint4*)(vT + (size_t)(vd + 32) * SEQ + vc * 8);
    {
        const int kswz = (kr & 7) << 4;
        *(uint4*)((char*)lsK[0] + kr * 128 + ((kc * 16) ^ kswz)) = kg0;
        *(uint4*)((char*)lsK[0] + (kr + 64) * 128 + ((kc * 16) ^ kswz)) = kg1;
        *(uint4*)((char*)lsV[0] + vd * 256 + ((vc * 16) ^ ((vd & 15) << 4))) = vg0;
        *(uint4*)((char*)lsV[0] + (vd + 32) * 256 + ((vc * 16) ^ (((vd + 32) & 15) << 4))) = vg1;
    }

    for (int t = 0; t < nt; ++t) {
        const int t0 = t << 7;
        const int cb = t & 1;
        // T14: issue next tile's global loads before compute
        if (t + 1 < nt) {
            const int t1 = t0 + 128;
            kg0 = *(const uint4*)(kb + (size_t)(t1 + kr) * 64 + kc * 8);
            kg1 = *(const uint4*)(kb + (size_t)(t1 + kr + 64) * 64 + kc * 8);
            vg0 = *(const uint4*)(vT + (size_t)vd * SEQ + t1 + vc * 8);
            vg1 = *(const uint4*)(vT + (size_t)(vd + 32) * SEQ + t1 + vc * 8);
        }
        __syncthreads();   // buf[cb] writes visible; everyone done with buf[cb] (prev use)

        // ---- S^T = K @ Q : sacc[mi][ni][jj] = S[q0+mi*16+l15][t0+ni*16+lg*4+jj]
        f32x4 sacc[2][8];
#pragma unroll
        for (int i = 0; i < 2; ++i)
#pragma unroll
            for (int j = 0; j < 8; ++j) sacc[i][j] = (f32x4){0.f, 0.f, 0.f, 0.f};
#pragma unroll
        for (int ni = 0; ni < 8; ++ni) {
            const int r = ni * 16 + l15;
            const int swz = (r & 7) << 4;
            bf16x8 kf0 = *(const bf16x8*)((const char*)lsK[cb] + r * 128 + ((lg * 16) ^ swz));
            bf16x8 kf1 = *(const bf16x8*)((const char*)lsK[cb] + r * 128 + ((64 + lg * 16) ^ swz));
            sacc[0][ni] = __builtin_amdgcn_mfma_f32_16x16x32_bf16(kf0, qf[0][0], sacc[0][ni], 0, 0, 0);
            sacc[1][ni] = __builtin_amdgcn_mfma_f32_16x16x32_bf16(kf0, qf[1][0], sacc[1][ni], 0, 0, 0);
            sacc[0][ni] = __builtin_amdgcn_mfma_f32_16x16x32_bf16(kf1, qf[0][1], sacc[0][ni], 0, 0, 0);
            sacc[1][ni] = __builtin_amdgcn_mfma_f32_16x16x32_bf16(kf1, qf[1][1], sacc[1][ni], 0, 0, 0);
        }
        const bool last = (t == nt - 1);

        // ---- online softmax (row q = q0 + mi*16 + l15, replicated over lg)
#pragma unroll
        for (int mi = 0; mi < 2; ++mi) {
            const int q = q0 + mi * 16 + l15;
            if (last) {
#pragma unroll
                for (int ni = 0; ni < 8; ++ni)
#pragma unroll
                    for (int jj = 0; jj < 4; ++jj)
                        if (t0 + ni * 16 + lg * 4 + jj > q) sacc[mi][ni][jj] = -1e9f;
            }
            float m = sacc[mi][0][0];
#pragma unroll
            for (int ni = 0; ni < 8; ++ni)
#pragma unroll
                for (int jj = 0; jj < 4; ++jj) m = fmaxf(m, sacc[mi][ni][jj]);
            m = fmaxf(m, __shfl_xor(m, 16, 64));
            m = fmaxf(m, __shfl_xor(m, 32, 64));
            float mnew = fmaxf(mrun[mi], m);
            float alpha = exp2f(mrun[mi] - mnew);
            float rs = 0.f;
#pragma unroll
            for (int ni = 0; ni < 8; ++ni)
#pragma unroll
                for (int jj = 0; jj < 4; ++jj) {
                    float p = exp2f(sacc[mi][ni][jj] - mnew);
                    sacc[mi][ni][jj] = p;
                    rs += p;
                }
            rs += __shfl_xor(rs, 16, 64);
            rs += __shfl_xor(rs, 32, 64);
            lrun[mi] = lrun[mi] * alpha + rs;
            mrun[mi] = mnew;

            // P -> wave-private LDS (b64 writes, swizzled)
            const int qh = mi * 16 + l15;
            const int pswz = (qh & 7) << 4;
#pragma unroll
            for (int ni = 0; ni < 8; ++ni) {
                u32 w0 = (u32)f2bf(sacc[mi][ni][0]) | ((u32)f2bf(sacc[mi][ni][1]) << 16);
                u32 w1 = (u32)f2bf(sacc[mi][ni][2]) | ((u32)f2bf(sacc[mi][ni][3]) << 16);
                uint2 w; w.x = w0; w.y = w1;
                *(uint2*)((char*)myP + qh * 256 + ((ni * 32 + lg * 8) ^ pswz)) = w;
            }
            // rescale O rows (row = lg*4+jj) by alpha from lane (lg*16 + lg*4+jj)
#pragma unroll
            for (int jj = 0; jj < 4; ++jj) {
                float aB = __shfl(alpha, (lane & 48) + ((lane >> 4) & 3) * 4 + jj, 64);
#pragma unroll
                for (int nd = 0; nd < 4; ++nd) oacc[mi][nd][jj] *= aB;
            }
        }

        // ---- O += P @ V
#pragma unroll
        for (int ks = 0; ks < 4; ++ks) {
            bf16x8 pf[2];
#pragma unroll
            for (int mi = 0; mi < 2; ++mi) {
                const int qh = mi * 16 + l15;
                pf[mi] = *(const bf16x8*)((const char*)myP + qh * 256
                                          + ((ks * 64 + lg * 16) ^ ((qh & 7) << 4)));
            }
#pragma unroll
            for (int nd = 0; nd < 4; ++nd) {
                const int r = nd * 16 + l15;
                bf16x8 vf = *(const bf16x8*)((const char*)lsV[cb] + r * 256
                                             + ((ks * 64 + lg * 16) ^ ((r & 15) << 4)));
                oacc[0][nd] = __builtin_amdgcn_mfma_f32_16x16x32_bf16(pf[0], vf, oacc[0][nd], 0, 0, 0);
                oacc[1][nd] = __builtin_amdgcn_mfma_f32_16x16x32_bf16(pf[1], vf, oacc[1][nd], 0, 0, 0);
            }
        }

        // write next tile into the other buffer (vmcnt wait lands here, after compute)
        if (t + 1 < nt) {
            const int nb = cb ^ 1;
            const int kswz = (kr & 7) << 4;
            *(uint4*)((char*)lsK[nb] + kr * 128 + ((kc * 16) ^ kswz)) = kg0;
            *(uint4*)((char*)lsK[nb] + (kr + 64) * 128 + ((kc * 16) ^ kswz)) = kg1;
            *(uint4*)((char*)lsV[nb] + vd * 256 + ((vc * 16) ^ ((vd & 15) << 4))) = vg0;
            *(uint4*)((char*)lsV[nb] + (vd + 32) * 256 + ((vc * 16) ^ (((vd + 32) & 15) << 4))) = vg1;
        }
    }

    // ---- epilogue: O /= l ; ctx[q][h*64+d]
    if (hval) {
#pragma unroll
        for (int mi = 0; mi < 2; ++mi)
#pragma unroll
            for (int jj = 0; jj < 4; ++jj) {
                float lB = __shfl(lrun[mi], (lane & 48) + ((lane >> 4) & 3) * 4 + jj, 64);
                float inv = 1.0f / lB;
                int q = q0 + mi * 16 + lg * 4 + jj;
#pragma unroll
                for (int nd = 0; nd < 4; ++nd)
                    ctx[(size_t)q * HID + h * 64 + nd * 16 + l15] = f2bf(oacc[mi][nd][jj] * inv);
            }
    }
}

extern "C" void kernel_launch(void* const* d_in, const int* in_sizes, int n_in,
                              void* d_out, int out_size, void* d_ws, size_t ws_size,
                              hipStream_t stream) {
    const float* hs      = (const float*)d_in[0];
    const float* w_qkv   = (const float*)d_in[2];
    const float* w_dense = (const float*)d_in[3];
    const float* cosb    = (const float*)d_in[4];
    const float* sinb    = (const float*)d_in[5];
    float* out = (float*)d_out;

    char* ws = (char*)d_ws;
    u16*   x_bf  = (u16*)(ws + 0);            // [2048][4544] bf16; reused as ctx
    u16*   wqkvT = (u16*)(ws + 18612224);     // [4736][4544] bf16
    u16*   wdenT = (u16*)(ws + 61652992);     // [4608][4544] bf16
    float* qkv   = (float*)(ws + 103530496);  // [2048][4672] f32
    u16*   q_bf  = (u16*)(ws + 141803520);    // [71][2048][64] bf16 (scaled)
    u16*   k_bf  = (u16*)(ws + 160415744);    // [2048][64] bf16
    u16*   vT_bf = (u16*)(ws + 160677888);    // [64][2048] bf16

    k_convert<<<2048, 256, 0, stream>>>(hs, x_bf, (SEQ * HID) / 4);
    k_transpose<<<dim3(NQKV / 32, HID / 32), 256, 0, stream>>>(w_qkv, wqkvT, HID, NQKV);
    k_transpose<<<dim3(HID / 32, HID / 32), 256, 0, stream>>>(w_dense, wdenT, HID, HID);
    k_gemm_bt<<<dim3(37, 16), 256, 0, stream>>>(x_bf, wqkvT, qkv, SEQ, NQKV, HID);
    k_rope<<<SEQ, 256, 0, stream>>>(qkv, cosb, sinb, q_bf, k_bf, vT_bf);
    k_attn<<<dim3(576), 512, 0, stream>>>(q_bf, k_bf, vT_bf, x_bf /*ctx*/);
    k_gemm_bt<<<dim3(36, 16), 256, 0, stream>>>(x_bf /*ctx*/, wdenT, out, SEQ, HID, HID);
}

// Round 4
// 506.308 us; speedup vs baseline: 1.5374x; 1.0144x over previous
//
#include <hip/hip_runtime.h>

typedef unsigned short u16;
typedef unsigned int u32;
typedef __attribute__((ext_vector_type(8))) __bf16 bf16x8;
typedef __attribute__((ext_vector_type(4))) float f32x4;

#define SEQ   2048
#define NH    71
#define HD    64
#define HID   4544   // 71*64
#define NQKV  4672   // 73*64
#define KP    4608   // K padded to 72*64 (even # of 64-wide K-tiles)

__device__ __forceinline__ u16 f2bf(float f) {
    __bf16 b = (__bf16)f;
    return __builtin_bit_cast(u16, b);
}

__device__ __forceinline__ void gload_lds16(const u16* g, u16* l) {
    __builtin_amdgcn_global_load_lds(
        (const __attribute__((address_space(1))) u32*)g,
        (__attribute__((address_space(3))) u32*)l, 16, 0, 0);
}

// ---------------- f32 -> bf16, K-padded rows (zero pad) ----------------
__global__ __launch_bounds__(256) void k_convert(const float* __restrict__ in,
                                                 u16* __restrict__ out) {
    const int row = blockIdx.x;
    const float* src = in + (size_t)row * HID;
    u16* dst = out + (size_t)row * KP;
    for (int c = threadIdx.x; c < KP / 8; c += 256) {
        u16 o[8];
        if (c < HID / 8) {
            float4 v0 = *(const float4*)(src + c * 8);
            float4 v1 = *(const float4*)(src + c * 8 + 4);
            o[0] = f2bf(v0.x); o[1] = f2bf(v0.y); o[2] = f2bf(v0.z); o[3] = f2bf(v0.w);
            o[4] = f2bf(v1.x); o[5] = f2bf(v1.y); o[6] = f2bf(v1.z); o[7] = f2bf(v1.w);
        } else {
#pragma unroll
            for (int j = 0; j < 8; ++j) o[j] = 0;
        }
        *(uint4*)(dst + c * 8) = *(uint4*)o;
    }
}

// ----- transpose+convert: in[R][C] f32 -> out[Cp][Rp] bf16, zero-padded -----
__global__ __launch_bounds__(256) void k_transpose(const float* __restrict__ in,
                                                   u16* __restrict__ out,
                                                   int R, int C, int Rp) {
    __shared__ float tile[32][33];
    int c0 = blockIdx.x * 32, r0 = blockIdx.y * 32;
    int tx = threadIdx.x & 31, ty = threadIdx.x >> 5;
#pragma unroll
    for (int i = 0; i < 32; i += 8) {
        int r = r0 + ty + i, c = c0 + tx;
        tile[ty + i][tx] = (r < R && c < C) ? in[(size_t)r * C + c] : 0.f;
    }
    __syncthreads();
#pragma unroll
    for (int i = 0; i < 32; i += 8)
        out[(size_t)(c0 + ty + i) * Rp + r0 + tx] = f2bf(tile[tx][ty + i]);
}

// ---- C[M][N] f32 = A[M][KP] bf16 @ BT[Npad][KP]^T ----
// 256x256 tile, BK=64, 8 waves (2M x 4N), double-buffered 128KB LDS.
// Pipeline: burst-stage next K-tile right after tile boundary (into the free
// dbuf), 4 MFMA phases (16 MFMA each) hide the latency, single drain at the
// tile-end __syncthreads. XOR-swizzled LDS rows (conflict-free, r3-verified).
// Chunked XCD swizzle: mt = lin&7 -> each XCD owns one A-panel row.
__global__ __launch_bounds__(512, 2) void k_gemm256(const u16* __restrict__ A,
                                                    const u16* __restrict__ BT,
                                                    float* __restrict__ C,
                                                    int N, int ldc) {
    __shared__ u16 lsA[2][256 * 64];
    __shared__ u16 lsB[2][256 * 64];
    const int tid = threadIdx.x;
    const int lane = tid & 63;
    const int wid = tid >> 6;
    const int wr = wid >> 2, wc = wid & 3;     // 2 x 4 wave grid (128 x 64 each)
    const int l15 = lane & 15, lg = lane >> 4;

    const int lin = blockIdx.y * gridDim.x + blockIdx.x;
    const int m0 = (lin & 7) * 256;
    const int n0 = (lin >> 3) * 256;

    // staging: per thread 8 gloads/K-tile; lds offset = j*4096 + tid*8 (lane-linear)
    const int srow = tid >> 3, sc = tid & 7;
    const u16* Ag = A + (size_t)(m0 + srow) * KP + (sc ^ (srow & 7)) * 8;
    const u16* Bg = BT + (size_t)(n0 + srow) * KP + (sc ^ (srow & 7)) * 8;

    f32x4 acc[8][4];
#pragma unroll
    for (int i = 0; i < 8; ++i)
#pragma unroll
        for (int j = 0; j < 4; ++j) acc[i][j] = (f32x4){0.f, 0.f, 0.f, 0.f};

#define STAGE(d, t)                                                                  \
    do {                                                                             \
        const size_t ko = (size_t)(t) * 64;                                          \
        _Pragma("unroll") for (int j = 0; j < 4; ++j)                                \
            gload_lds16(Ag + (size_t)j * 64 * KP + ko,                               \
                        lsA[d] + (j * 64 + srow) * 64 + sc * 8);                     \
        _Pragma("unroll") for (int j = 0; j < 4; ++j)                                \
            gload_lds16(Bg + (size_t)j * 64 * KP + ko,                               \
                        lsB[d] + (j * 64 + srow) * 64 + sc * 8);                     \
    } while (0)

    STAGE(0, 0);
    __syncthreads();

    const int NT = KP / 64;  // 72
    for (int t = 0; t < NT; ++t) {
        const int d = t & 1;
        if (t + 1 < NT) STAGE(d ^ 1, t + 1);
        const u16* La = lsA[d];
        const u16* Lb = lsB[d];
        bf16x8 bfr[4], af[4];
        // ---- phase 1: kk=0, mi 0..3
#pragma unroll
        for (int ni = 0; ni < 4; ++ni) {
            int r = wc * 64 + ni * 16 + l15;
            bfr[ni] = *(const bf16x8*)(Lb + r * 64 + ((lg ^ (r & 7)) << 3));
        }
#pragma unroll
        for (int mi = 0; mi < 4; ++mi) {
            int r = wr * 128 + mi * 16 + l15;
            af[mi] = *(const bf16x8*)(La + r * 64 + ((lg ^ (r & 7)) << 3));
        }
        __builtin_amdgcn_s_setprio(1);
#pragma unroll
        for (int mi = 0; mi < 4; ++mi)
#pragma unroll
            for (int ni = 0; ni < 4; ++ni)
                acc[mi][ni] = __builtin_amdgcn_mfma_f32_16x16x32_bf16(
                    af[mi], bfr[ni], acc[mi][ni], 0, 0, 0);
        __builtin_amdgcn_s_setprio(0);
        __builtin_amdgcn_s_barrier();
        // ---- phase 2: kk=0, mi 4..7
#pragma unroll
        for (int mi = 0; mi < 4; ++mi) {
            int r = wr * 128 + (mi + 4) * 16 + l15;
            af[mi] = *(const bf16x8*)(La + r * 64 + ((lg ^ (r & 7)) << 3));
        }
        __builtin_amdgcn_s_setprio(1);
#pragma unroll
        for (int mi = 0; mi < 4; ++mi)
#pragma unroll
            for (int ni = 0; ni < 4; ++ni)
                acc[mi + 4][ni] = __builtin_amdgcn_mfma_f32_16x16x32_bf16(
                    af[mi], bfr[ni], acc[mi + 4][ni], 0, 0, 0);
        __builtin_amdgcn_s_setprio(0);
        __builtin_amdgcn_s_barrier();
        // ---- phase 3: kk=1, mi 0..3
#pragma unroll
        for (int ni = 0; ni < 4; ++ni) {
            int r = wc * 64 + ni * 16 + l15;
            bfr[ni] = *(const bf16x8*)(Lb + r * 64 + (((4 + lg) ^ (r & 7)) << 3));
        }
#pragma unroll
        for (int mi = 0; mi < 4; ++mi) {
            int r = wr * 128 + mi * 16 + l15;
            af[mi] = *(const bf16x8*)(La + r * 64 + (((4 + lg) ^ (r & 7)) << 3));
        }
        __builtin_amdgcn_s_setprio(1);
#pragma unroll
        for (int mi = 0; mi < 4; ++mi)
#pragma unroll
            for (int ni = 0; ni < 4; ++ni)
                acc[mi][ni] = __builtin_amdgcn_mfma_f32_16x16x32_bf16(
                    af[mi], bfr[ni], acc[mi][ni], 0, 0, 0);
        __builtin_amdgcn_s_setprio(0);
        __builtin_amdgcn_s_barrier();
        // ---- phase 4: kk=1, mi 4..7
#pragma unroll
        for (int mi = 0; mi < 4; ++mi) {
            int r = wr * 128 + (mi + 4) * 16 + l15;
            af[mi] = *(const bf16x8*)(La + r * 64 + (((4 + lg) ^ (r & 7)) << 3));
        }
        __builtin_amdgcn_s_setprio(1);
#pragma unroll
        for (int mi = 0; mi < 4; ++mi)
#pragma unroll
            for (int ni = 0; ni < 4; ++ni)
                acc[mi + 4][ni] = __builtin_amdgcn_mfma_f32_16x16x32_bf16(
                    af[mi], bfr[ni], acc[mi + 4][ni], 0, 0, 0);
        __builtin_amdgcn_s_setprio(0);
        __syncthreads();   // vmcnt(0)+lgkmcnt(0)+barrier: next tile landed, dbuf swap
    }
#undef STAGE

#pragma unroll
    for (int mi = 0; mi < 8; ++mi)
#pragma unroll
        for (int ni = 0; ni < 4; ++ni) {
            int row = m0 + wr * 128 + mi * 16 + lg * 4;
            int col = n0 + wc * 64 + ni * 16 + l15;
            if (col < N) {
#pragma unroll
                for (int j = 0; j < 4; ++j)
                    C[(size_t)(row + j) * ldc + col] = acc[mi][ni][j];
            }
        }
}

// ---------------- RoPE + split/transposed emit ----------------
// q pre-scaled by (1/8)*log2(e) so attention softmax can use exp2 directly.
__global__ __launch_bounds__(256) void k_rope(const float* __restrict__ qkv,
                                              const float* __restrict__ cosb,
                                              const float* __restrict__ sinb,
                                              u16* __restrict__ qb, u16* __restrict__ kb,
                                              u16* __restrict__ vT) {
    int s = blockIdx.x;
    __shared__ float cs[64], sn[64];
    if (threadIdx.x < 64) {
        cs[threadIdx.x] = cosb[s * 64 + threadIdx.x];
        sn[threadIdx.x] = sinb[s * 64 + threadIdx.x];
    }
    __syncthreads();
    const float* row = qkv + (size_t)s * NQKV;
    const float qscale = 0.125f * 1.44269504f;
    for (int e = threadIdx.x; e < NQKV; e += 256) {
        int h = e >> 6, d = e & 63;
        float x = row[e];
        if (h < 72) {
            float other = row[h * 64 + ((d < 32) ? d + 32 : d - 32)];
            float rot = (d < 32) ? -other : other;
            float r = x * cs[d] + rot * sn[d];
            if (h < NH) qb[((size_t)h * SEQ + s) * 64 + d] = f2bf(r * qscale);
            else        kb[(size_t)s * 64 + d] = f2bf(r);
        } else {
            vT[(size_t)d * SEQ + s] = f2bf(x);
        }
    }
}

// ---------------- Flash attention: MQA head-group sharing + dbuf staging ----------------
// Block = 512 threads (8 waves) = (q-tile of 32 rows, group of 8 heads); wave w -> head
// hg*8+w, all waves share the staged K/V tile. KV tiles of 128, double-buffered LDS with
// T14 async split. Swapped QK^T (S^T = K@Q) for lane-local softmax rows.
// ctx written with row stride KP; the spare wave (h==71) zero-fills ctx pad cols.
__global__ __launch_bounds__(512) void k_attn(const u16* __restrict__ qb,
                                              const u16* __restrict__ kb,
                                              const u16* __restrict__ vT,
                                              u16* __restrict__ ctx) {
    const int tid = threadIdx.x;
    const int lane = tid & 63;
    const int wid = tid >> 6;           // 0..7
    const int l15 = lane & 15, lg = lane >> 4;

    const int bid = blockIdx.x;         // 0..575
    const int qt = 63 - bid / 9;        // long blocks dispatch first
    const int hg = bid % 9;
    int h = hg * 8 + wid;
    const bool hval = (h < NH);
    if (!hval) h = NH - 1;
    const int q0 = qt * 32;
    const int nt = (qt >> 2) + 1;

    __shared__ u16 lsK[2][128 * 64];    // [t][d] rows 128B, XOR-swizzled
    __shared__ u16 lsV[2][64 * 128];    // [d][t] rows 256B, XOR-swizzled
    __shared__ u16 lsP[8][32 * 128];    // per-wave P, rows 256B, XOR-swizzled
    u16* myP = lsP[wid];

    const int kr = tid >> 3, kc = tid & 7;    // K-stage: rows kr and kr+64
    const int vd = tid >> 4, vc = tid & 15;   // V-stage: rows vd and vd+32

    bf16x8 qf[2][2];
#pragma unroll
    for (int mi = 0; mi < 2; ++mi)
#pragma unroll
        for (int ks = 0; ks < 2; ++ks)
            qf[mi][ks] = *(const bf16x8*)(qb + ((size_t)h * SEQ + q0 + mi * 16 + l15) * 64
                                          + ks * 32 + lg * 8);

    f32x4 oacc[2][4];
#pragma unroll
    for (int i = 0; i < 2; ++i)
#pragma unroll
        for (int j = 0; j < 4; ++j) oacc[i][j] = (f32x4){0.f, 0.f, 0.f, 0.f};
    float mrun[2] = {-3e38f, -3e38f};
    float lrun[2] = {0.f, 0.f};

    uint4 kg0, kg1, vg0, vg1;
    kg0 = *(const uint4*)(kb + (size_t)kr * 64 + kc * 8);
    kg1 = *(const uint4*)(kb + (size_t)(kr + 64) * 64 + kc * 8);
    vg0 = *(const uint4*)(vT + (size_t)vd * SEQ + vc * 8);
    vg1 = *(const uint4*)(vT + (size_t)(vd + 32) * SEQ + vc * 8);
    {
        const int kswz = (kr & 7) << 4;
        *(uint4*)((char*)lsK[0] + kr * 128 + ((kc * 16) ^ kswz)) = kg0;
        *(uint4*)((char*)lsK[0] + (kr + 64) * 128 + ((kc * 16) ^ kswz)) = kg1;
        *(uint4*)((char*)lsV[0] + vd * 256 + ((vc * 16) ^ ((vd & 15) << 4))) = vg0;
        *(uint4*)((char*)lsV[0] + (vd + 32) * 256 + ((vc * 16) ^ (((vd + 32) & 15) << 4))) = vg1;
    }

    for (int t = 0; t < nt; ++t) {
        const int t0 = t << 7;
        const int cb = t & 1;
        if (t + 1 < nt) {
            const int t1 = t0 + 128;
            kg0 = *(const uint4*)(kb + (size_t)(t1 + kr) * 64 + kc * 8);
            kg1 = *(const uint4*)(kb + (size_t)(t1 + kr + 64) * 64 + kc * 8);
            vg0 = *(const uint4*)(vT + (size_t)vd * SEQ + t1 + vc * 8);
            vg1 = *(const uint4*)(vT + (size_t)(vd + 32) * SEQ + t1 + vc * 8);
        }
        __syncthreads();

        f32x4 sacc[2][8];
#pragma unroll
        for (int i = 0; i < 2; ++i)
#pragma unroll
            for (int j = 0; j < 8; ++j) sacc[i][j] = (f32x4){0.f, 0.f, 0.f, 0.f};
#pragma unroll
        for (int ni = 0; ni < 8; ++ni) {
            const int r = ni * 16 + l15;
            const int swz = (r & 7) << 4;
            bf16x8 kf0 = *(const bf16x8*)((const char*)lsK[cb] + r * 128 + ((lg * 16) ^ swz));
            bf16x8 kf1 = *(const bf16x8*)((const char*)lsK[cb] + r * 128 + ((64 + lg * 16) ^ swz));
            sacc[0][ni] = __builtin_amdgcn_mfma_f32_16x16x32_bf16(kf0, qf[0][0], sacc[0][ni], 0, 0, 0);
            sacc[1][ni] = __builtin_amdgcn_mfma_f32_16x16x32_bf16(kf0, qf[1][0], sacc[1][ni], 0, 0, 0);
            sacc[0][ni] = __builtin_amdgcn_mfma_f32_16x16x32_bf16(kf1, qf[0][1], sacc[0][ni], 0, 0, 0);
            sacc[1][ni] = __builtin_amdgcn_mfma_f32_16x16x32_bf16(kf1, qf[1][1], sacc[1][ni], 0, 0, 0);
        }
        const bool last = (t == nt - 1);

#pragma unroll
        for (int mi = 0; mi < 2; ++mi) {
            const int q = q0 + mi * 16 + l15;
            if (last) {
#pragma unroll
                for (int ni = 0; ni < 8; ++ni)
#pragma unroll
                    for (int jj = 0; jj < 4; ++jj)
                        if (t0 + ni * 16 + lg * 4 + jj > q) sacc[mi][ni][jj] = -1e9f;
            }
            float m = sacc[mi][0][0];
#pragma unroll
            for (int ni = 0; ni < 8; ++ni)
#pragma unroll
                for (int jj = 0; jj < 4; ++jj) m = fmaxf(m, sacc[mi][ni][jj]);
            m = fmaxf(m, __shfl_xor(m, 16, 64));
            m = fmaxf(m, __shfl_xor(m, 32, 64));
            float mnew = fmaxf(mrun[mi], m);
            float alpha = exp2f(mrun[mi] - mnew);
            float rs = 0.f;
#pragma unroll
            for (int ni = 0; ni < 8; ++ni)
#pragma unroll
                for (int jj = 0; jj < 4; ++jj) {
                    float p = exp2f(sacc[mi][ni][jj] - mnew);
                    sacc[mi][ni][jj] = p;
                    rs += p;
                }
            rs += __shfl_xor(rs, 16, 64);
            rs += __shfl_xor(rs, 32, 64);
            lrun[mi] = lrun[mi] * alpha + rs;
            mrun[mi] = mnew;

            const int qh = mi * 16 + l15;
            const int pswz = (qh & 7) << 4;
#pragma unroll
            for (int ni = 0; ni < 8; ++ni) {
                u32 w0 = (u32)f2bf(sacc[mi][ni][0]) | ((u32)f2bf(sacc[mi][ni][1]) << 16);
                u32 w1 = (u32)f2bf(sacc[mi][ni][2]) | ((u32)f2bf(sacc[mi][ni][3]) << 16);
                uint2 w; w.x = w0; w.y = w1;
                *(uint2*)((char*)myP + qh * 256 + ((ni * 32 + lg * 8) ^ pswz)) = w;
            }
#pragma unroll
            for (int jj = 0; jj < 4; ++jj) {
                float aB = __shfl(alpha, (lane & 48) + ((lane >> 4) & 3) * 4 + jj, 64);
#pragma unroll
                for (int nd = 0; nd < 4; ++nd) oacc[mi][nd][jj] *= aB;
            }
        }

#pragma unroll
        for (int ks = 0; ks < 4; ++ks) {
            bf16x8 pf[2];
#pragma unroll
            for (int mi = 0; mi < 2; ++mi) {
                const int qh = mi * 16 + l15;
                pf[mi] = *(const bf16x8*)((const char*)myP + qh * 256
                                          + ((ks * 64 + lg * 16) ^ ((qh & 7) << 4)));
            }
#pragma unroll
            for (int nd = 0; nd < 4; ++nd) {
                const int r = nd * 16 + l15;
                bf16x8 vf = *(const bf16x8*)((const char*)lsV[cb] + r * 256
                                             + ((ks * 64 + lg * 16) ^ ((r & 15) << 4)));
                oacc[0][nd] = __builtin_amdgcn_mfma_f32_16x16x32_bf16(pf[0], vf, oacc[0][nd], 0, 0, 0);
                oacc[1][nd] = __builtin_amdgcn_mfma_f32_16x16x32_bf16(pf[1], vf, oacc[1][nd], 0, 0, 0);
            }
        }

        if (t + 1 < nt) {
            const int nb = cb ^ 1;
            const int kswz = (kr & 7) << 4;
            *(uint4*)((char*)lsK[nb] + kr * 128 + ((kc * 16) ^ kswz)) = kg0;
            *(uint4*)((char*)lsK[nb] + (kr + 64) * 128 + ((kc * 16) ^ kswz)) = kg1;
            *(uint4*)((char*)lsV[nb] + vd * 256 + ((vc * 16) ^ ((vd & 15) << 4))) = vg0;
            *(uint4*)((char*)lsV[nb] + (vd + 32) * 256 + ((vc * 16) ^ (((vd + 32) & 15) << 4))) = vg1;
        }
    }

    if (hval) {
#pragma unroll
        for (int mi = 0; mi < 2; ++mi)
#pragma unroll
            for (int jj = 0; jj < 4; ++jj) {
                float lB = __shfl(lrun[mi], (lane & 48) + ((lane >> 4) & 3) * 4 + jj, 64);
                float inv = 1.0f / lB;
                int q = q0 + mi * 16 + lg * 4 + jj;
#pragma unroll
                for (int nd = 0; nd < 4; ++nd)
                    ctx[(size_t)q * KP + h * 64 + nd * 16 + l15] = f2bf(oacc[mi][nd][jj] * inv);
            }
    } else {
        // zero-fill ctx K-pad columns (4544..4607) for this block's 32 rows
#pragma unroll
        for (int mi = 0; mi < 2; ++mi)
#pragma unroll
            for (int jj = 0; jj < 4; ++jj) {
                int q = q0 + mi * 16 + lg * 4 + jj;
#pragma unroll
                for (int nd = 0; nd < 4; ++nd)
                    ctx[(size_t)q * KP + HID + nd * 16 + l15] = 0;
            }
    }
}

extern "C" void kernel_launch(void* const* d_in, const int* in_sizes, int n_in,
                              void* d_out, int out_size, void* d_ws, size_t ws_size,
                              hipStream_t stream) {
    const float* hs      = (const float*)d_in[0];
    const float* w_qkv   = (const float*)d_in[2];
    const float* w_dense = (const float*)d_in[3];
    const float* cosb    = (const float*)d_in[4];
    const float* sinb    = (const float*)d_in[5];
    float* out = (float*)d_out;

    char* ws = (char*)d_ws;
    // workspace layout (bytes); wdenT overlaps qkv+q_bf head (both dead by then)
    u16*   x_bf  = (u16*)(ws + 0);            // [2048][4608] bf16; reused as ctx
    u16*   wqkvT = (u16*)(ws + 18874368);     // [4864][4608] bf16
    float* qkv   = (float*)(ws + 63700992);   // [2048][4672] f32
    u16*   q_bf  = (u16*)(ws + 101974016);    // [71][2048][64] bf16 (scaled)
    u16*   k_bf  = (u16*)(ws + 120586240);    // [2048][64] bf16
    u16*   vT_bf = (u16*)(ws + 120848384);    // [64][2048] bf16  (end 121110528)
    u16*   wdenT = (u16*)(ws + 63700992);     // [4608][4608] bf16 (overlaps qkv/q_bf)

    k_convert<<<2048, 256, 0, stream>>>(hs, x_bf);
    k_transpose<<<dim3(152, 144), 256, 0, stream>>>(w_qkv, wqkvT, HID, NQKV, KP);
    k_gemm256<<<dim3(19, 8), 512, 0, stream>>>(x_bf, wqkvT, qkv, NQKV, NQKV);
    k_rope<<<SEQ, 256, 0, stream>>>(qkv, cosb, sinb, q_bf, k_bf, vT_bf);
    k_attn<<<dim3(576), 512, 0, stream>>>(q_bf, k_bf, vT_bf, x_bf /*ctx*/);
    k_transpose<<<dim3(144, 144), 256, 0, stream>>>(w_dense, wdenT, HID, HID, KP);
    k_gemm256<<<dim3(18, 8), 512, 0, stream>>>(x_bf /*ctx*/, wdenT, out, HID, HID);
}